// Round 7
// baseline (138.766 us; speedup 1.0000x reference)
//
#include <hip/hip_runtime.h>
#include <stdint.h>

// Problem dims
#define B_DIM 8192
#define I_DIM 512
#define O_DIM 512
#define KDIM  2048   // I_DIM * 4 features: {silu, u0, u1, u2}

// GEMM tile
#define BM 128
#define BN 64
#define BK 64        // two 32-wide halves; LDS layout [kh][rows][32]

using bf16x8 = __attribute__((ext_vector_type(8))) short;
using f32x4  = __attribute__((ext_vector_type(4))) float;

__device__ __forceinline__ unsigned short f2bf(float f) {
  union { float f; unsigned int u; } c; c.f = f;
  unsigned int x = c.u;
  unsigned int r = (x + 0x7fffu + ((x >> 16) & 1u)) >> 16;  // RNE
  return (unsigned short)r;
}

// silu + basis-interp features for one x value -> 4 bf16 (exact same op
// sequence as the old build_a kernel => bit-identical outputs).
__device__ __forceinline__ void feat4(float xf, unsigned short* o) {
  const float s = xf / (1.0f + __expf(-xf));          // silu, f32
  const float xc = fminf(fmaxf(xf, -1.0f), 1.0f);
  const float g = xc + 1.0f;                          // grid_idx in [0,2]
  int il = (int)floorf(g);
  if (il > 2) il = 2;
  const float fr = g - (float)il;
  int ih = il + (fr > 0.0f ? 1 : 0);
  if (ih > 2) ih = 2;
  const float u0 = (il == 0 ? 1.0f - fr : 0.0f) + (ih == 0 ? fr : 0.0f);
  const float u1 = (il == 1 ? 1.0f - fr : 0.0f) + (ih == 1 ? fr : 0.0f);
  const float u2 = (il == 2 ? 1.0f - fr : 0.0f) + (ih == 2 ? fr : 0.0f);
  o[0] = f2bf(s); o[1] = f2bf(u0); o[2] = f2bf(u1); o[3] = f2bf(u2);
}

// ---------------------------------------------------------------------------
// Prologue: only W now. Wt[o][i*4+0]=imp*bw ; Wt[o][i*4+1+g]=(BASIS[g]·cp)*imp*sw
// (N-major). BASIS: Gaussian pseudo-B-spline, knots linspace(-1.3,1.3,9),
// width .65, centers {-.8125,-.4875,-.1625,.1625,.4875}, rows norm'd (+1e-6).
// ---------------------------------------------------------------------------
__global__ __launch_bounds__(256) void build_w(const float* __restrict__ cp,
                                               const float* __restrict__ bw,
                                               const float* __restrict__ sw,
                                               const float* __restrict__ imp,
                                               unsigned short* __restrict__ Wt) {
  const int idx = blockIdx.x * 256 + threadIdx.x;
  const int i = idx >> 9;
  const int o = idx & 511;
  const int e = i * O_DIM + o;
  const float im = imp[e];
  const float wb = im * bw[e];
  const float wsp = im * sw[e];
  const float* c = cp + (size_t)e * 5;
  const float c0 = c[0], c1 = c[1], c2 = c[2], c3 = c[3], c4 = c[4];
  const float q0 = (0.54336160f * c0 + 0.31713055f * c1 + 0.11226386f * c2 +
                    0.02410431f * c3 + 0.00313908f * c4) * wsp;
  const float q1 = (0.06493530f * c0 + 0.17651242f * c1 + 0.29101978f * c2 +
                    0.29101978f * c3 + 0.17651242f * c4) * wsp;
  const float q2 = (0.00313908f * c0 + 0.02410431f * c1 + 0.11226386f * c2 +
                    0.31713055f * c3 + 0.54336160f * c4) * wsp;
  ushort4 v;
  v.x = f2bf(wb); v.y = f2bf(q0); v.z = f2bf(q1); v.w = f2bf(q2);
  *reinterpret_cast<ushort4*>(Wt + (size_t)o * KDIM + i * 4) = v;
}

// ---------------------------------------------------------------------------
// Fused GEMM: C = A(x)[M,K] * Wt[N,K]^T.  A is NEVER materialized in HBM:
// each thread loads 4 float2 of x per K-tile (slot k-range = 2 consecutive
// i's), computes {silu,u0,u1,u2} in VALU (overlaps MFMA, m114), ds_writes
// the A-subtile.  B keeps the 3-deep global_load_lds pipeline.
// Sync: A(t+2) written at phase t into buf freed at phase t-1's bar#2; the
// compiler's own vmcnt wait for x(t+2) (issued phase t-1) drains all older
// VMEM incl. B(t+1) => every bar#1 sees its B landed; no manual WAITV needed
// in the main loop (wait-chain induction).  lgkmcnt(0) before bar#1 makes
// prior-phase ds_writes visible.  Tail: WAITV(0) only for tile 31.
// ---------------------------------------------------------------------------
__device__ __forceinline__ void gload16(const void* g, void* lds) {
  __builtin_amdgcn_global_load_lds(
      (const __attribute__((address_space(1))) unsigned int*)g,
      (__attribute__((address_space(3))) unsigned int*)lds,
      16, 0, 0);
}

#define WAITV0   asm volatile("s_waitcnt vmcnt(0)" ::: "memory")
#define WAITLGKM asm volatile("s_waitcnt lgkmcnt(0)" ::: "memory")
#define BAR      __builtin_amdgcn_s_barrier()

__global__ __launch_bounds__(256, 2) void gemm(const float* __restrict__ x,
                                               const unsigned short* __restrict__ Wt,
                                               float* __restrict__ C) {
  // [buf][kh][rows][32] elems: A 3*2*128*32, B 3*2*64*32  -> 72 KB total
  __shared__ __align__(16) unsigned short As[3 * 8192];
  __shared__ __align__(16) unsigned short Bs[3 * 4096];

  // T1: XCD-aware swizzle (8 XCDs, 512 blocks, bijective since 512%8==0).
  const int bid = blockIdx.x;
  const int nb = (bid & 7) * 64 + (bid >> 3);
  const int mt = nb >> 3;
  const int nt = nb & 7;
  const int m0 = mt * BM;
  const int n0 = nt * BN;

  const int t = threadIdx.x;
  const int l = t & 63;
  const int w = t >> 6;
  const int wm = w >> 1;     // 2 m-halves of 64 rows
  const int wn = w & 1;      // 2 n-halves of 32 cols
  const int lr = l & 15;
  const int kg = (l >> 4) * 8;

  f32x4 acc[4][2] = {};

  // A-slot map: slot s (<1024) = [kh][row][c] -> k = kh*32+c*8+{0..7}
  //  -> i-pair i0 = kh*8+c*2 (+ tile*16): ONE aligned float2 of x per slot.
  const float* xp[4];
  int aoffw[4];
#pragma unroll
  for (int i = 0; i < 4; ++i) {
    const int s = t + 256 * i;
    const int kh = s >> 9, row = (s >> 2) & 127, c = s & 3;
    xp[i] = x + (size_t)(m0 + row) * I_DIM + kh * 8 + c * 2;
    aoffw[i] = s * 8;  // elem offset in A-region (16B aligned)
  }
  // B staging (global_load_lds, unchanged)
  const unsigned short* gB[2];
  unsigned short* lB[3][2];
#pragma unroll
  for (int i = 0; i < 2; ++i) {
    const int s = t + 256 * i;
    const int kh = s >> 8, row = (s >> 2) & 63, c = s & 3;
    gB[i] = Wt + (size_t)(n0 + row) * KDIM + kh * 32 + c * 8;
    lB[0][i] = Bs + s * 8;
    lB[1][i] = Bs + 4096 + s * 8;
    lB[2][i] = Bs + 8192 + s * 8;
  }

  const int aoff = (wm * 64 + lr) * 32 + kg;   // + m*512 + kh*4096
  const int boff = (wn * 32 + lr) * 32 + kg;   // + n*512 + kh*2048

  float2 xa[4];  // x data for tile (t+2) in steady state; static indices only

#define LOADX(tile) do {                                                       \
    _Pragma("unroll") for (int i = 0; i < 4; ++i)                              \
      xa[i] = *reinterpret_cast<const float2*>(xp[i] + (tile) * 16);           \
  } while (0)

#define WRITEA(pbuf) do {                                                      \
    _Pragma("unroll") for (int i = 0; i < 4; ++i) {                            \
      union { unsigned short us[8]; uint4 v; } ou;                             \
      feat4(xa[i].x, ou.us);                                                   \
      feat4(xa[i].y, ou.us + 4);                                               \
      *reinterpret_cast<uint4*>(&As[(pbuf) * 8192 + aoffw[i]]) = ou.v;         \
    }                                                                          \
  } while (0)

#define GLOADB(pbuf, tile) do {                                                \
    const int ko = (tile) * BK;                                                \
    _Pragma("unroll") for (int i = 0; i < 2; ++i)                              \
      gload16(gB[i] + ko, lB[pbuf][i]);                                        \
  } while (0)

#define COMPUTE(buf) do {                                                      \
    const unsigned short* Ab = As + (buf) * 8192;                              \
    const unsigned short* Bb = Bs + (buf) * 4096;                              \
    bf16x8 af[2][4], bfr[2][2];                                                \
    _Pragma("unroll") for (int h = 0; h < 2; ++h)                              \
      _Pragma("unroll") for (int m = 0; m < 4; ++m)                            \
        af[h][m] = *reinterpret_cast<const bf16x8*>(Ab + h * 4096 + aoff + m * 512); \
    _Pragma("unroll") for (int h = 0; h < 2; ++h)                              \
      _Pragma("unroll") for (int n = 0; n < 2; ++n)                            \
        bfr[h][n] = *reinterpret_cast<const bf16x8*>(Bb + h * 2048 + boff + n * 512); \
    _Pragma("unroll") for (int h = 0; h < 2; ++h)                              \
      _Pragma("unroll") for (int m = 0; m < 4; ++m)                            \
        _Pragma("unroll") for (int n = 0; n < 2; ++n)                          \
          acc[m][n] = __builtin_amdgcn_mfma_f32_16x16x32_bf16(af[h][m], bfr[h][n], acc[m][n], 0, 0, 0); \
  } while (0)

// Full phase, compile-time buf p, runtime tile tt (A(tt+2), B(tt+3) valid).
#define PHASEF(p, tt) do {                                                     \
    WAITLGKM; BAR;                                                             \
    COMPUTE(p);                                                                \
    BAR;                                                                       \
    WRITEA(((p) + 2) % 3);   /* A(tt+2) from xa = x(tt+2) */                   \
    LOADX((tt) + 3);                                                           \
    GLOADB(p, (tt) + 3);                                                       \
  } while (0)

  // Prologue: tiles 0..2 in flight; A(0),A(1) written; xa holds x(2).
  LOADX(0); GLOADB(0, 0);
  WRITEA(0);
  LOADX(1); GLOADB(1, 1);
  WRITEA(1);
  LOADX(2); GLOADB(2, 2);

#pragma unroll 1
  for (int tl = 0; tl < 27; tl += 3) {
    PHASEF(0, tl);
    PHASEF(1, tl + 1);
    PHASEF(2, tl + 2);
  }
  PHASEF(0, 27);
  PHASEF(1, 28);
  // t=29 (p=2): write A(31), no more issues
  WAITLGKM; BAR;
  COMPUTE(2);
  BAR;
  WRITEA(1);               // A(31) -> buf1, from xa = x(31)
  // t=30 (p=0)
  WAITLGKM; BAR;
  COMPUTE(0);
  BAR;
  // t=31 (p=1): B(31) has no younger x-wait -> force it
  WAITV0; WAITLGKM; BAR;
  COMPUTE(1);

#undef PHASEF
#undef COMPUTE
#undef GLOADB
#undef WRITEA
#undef LOADX

  // Epilogue: C/D layout col = lane&15, row = (lane>>4)*4 + reg [m89]
#pragma unroll
  for (int m = 0; m < 4; ++m) {
#pragma unroll
    for (int n = 0; n < 2; ++n) {
      const int col = n0 + wn * 32 + n * 16 + lr;
      const int rbase = m0 + wm * 64 + m * 16 + (l >> 4) * 4;
#pragma unroll
      for (int r = 0; r < 4; ++r)
        C[(size_t)(rbase + r) * O_DIM + col] = acc[m][n][r];
    }
  }
}

// ---------------------------------------------------------------------------
extern "C" void kernel_launch(void* const* d_in, const int* in_sizes, int n_in,
                              void* d_out, int out_size, void* d_ws, size_t ws_size,
                              hipStream_t stream) {
  const float* x   = (const float*)d_in[0];
  const float* cp  = (const float*)d_in[1];
  const float* bw  = (const float*)d_in[2];
  const float* sw  = (const float*)d_in[3];
  const float* imp = (const float*)d_in[4];
  float* out = (float*)d_out;

  unsigned short* Wbuf = (unsigned short*)d_ws;   // [512][2048] bf16 = 2 MB

  build_w<<<(I_DIM * O_DIM) / 256, 256, 0, stream>>>(cp, bw, sw, imp, Wbuf);
  gemm<<<(B_DIM / BM) * (O_DIM / BN), 256, 0, stream>>>(x, Wbuf, out);
}

// Round 8
// 109.695 us; speedup vs baseline: 1.2650x; 1.2650x over previous
//
#include <hip/hip_runtime.h>
#include <stdint.h>

// Problem dims
#define B_DIM 8192
#define I_DIM 512
#define O_DIM 512
#define KDIM  2048   // I_DIM * 4 features: {silu, u0, u1, u2}

// GEMM tile
#define BM 128
#define BN 64
#define BK 64        // two 32-wide halves; LDS layout [kh][rows][32]

using bf16x8 = __attribute__((ext_vector_type(8))) short;
using f32x4  = __attribute__((ext_vector_type(4))) float;

__device__ __forceinline__ unsigned short f2bf(float f) {
  union { float f; unsigned int u; } c; c.f = f;
  unsigned int x = c.u;
  unsigned int r = (x + 0x7fffu + ((x >> 16) & 1u)) >> 16;  // RNE
  return (unsigned short)r;
}

// ---------------------------------------------------------------------------
// Fused prologue. Blocks [0, 4096): A[b][i*4+{0..3}] = {silu(x), u0, u1, u2}.
// Blocks [4096, 5120): Wt[o][i*4+0]=imp*bw ; Wt[o][i*4+1+g]=(BASIS[g]·cp)*imp*sw
// ---------------------------------------------------------------------------
__global__ __launch_bounds__(256) void build_aw(const float* __restrict__ x,
                                                const float* __restrict__ cp,
                                                const float* __restrict__ bw,
                                                const float* __restrict__ sw,
                                                const float* __restrict__ imp,
                                                unsigned short* __restrict__ A,
                                                unsigned short* __restrict__ Wt) {
  if (blockIdx.x < 4096) {
    const int idx = blockIdx.x * 256 + threadIdx.x;
    const int b = idx >> 7;
    const int q = idx & 127;
    const float4 xv = *reinterpret_cast<const float4*>(x + (size_t)b * I_DIM + q * 4);
    union { unsigned short us[16]; uint4 v[2]; } out;
    const float xs[4] = {xv.x, xv.y, xv.z, xv.w};
#pragma unroll
    for (int j = 0; j < 4; ++j) {
      const float xf = xs[j];
      const float s = xf / (1.0f + __expf(-xf));          // silu, f32
      const float xc = fminf(fmaxf(xf, -1.0f), 1.0f);
      const float g = xc + 1.0f;                          // grid_idx in [0,2]
      int il = (int)floorf(g);
      if (il > 2) il = 2;
      const float fr = g - (float)il;
      int ih = il + (fr > 0.0f ? 1 : 0);
      if (ih > 2) ih = 2;
      const float u0 = (il == 0 ? 1.0f - fr : 0.0f) + (ih == 0 ? fr : 0.0f);
      const float u1 = (il == 1 ? 1.0f - fr : 0.0f) + (ih == 1 ? fr : 0.0f);
      const float u2 = (il == 2 ? 1.0f - fr : 0.0f) + (ih == 2 ? fr : 0.0f);
      out.us[j * 4 + 0] = f2bf(s);
      out.us[j * 4 + 1] = f2bf(u0);
      out.us[j * 4 + 2] = f2bf(u1);
      out.us[j * 4 + 3] = f2bf(u2);
    }
    uint4* dst = reinterpret_cast<uint4*>(A + (size_t)b * KDIM + q * 16);
    dst[0] = out.v[0];
    dst[1] = out.v[1];
  } else {
    const int idx = (blockIdx.x - 4096) * 256 + threadIdx.x;
    const int i = idx >> 9;
    const int o = idx & 511;
    const int e = i * O_DIM + o;
    const float im = imp[e];
    const float wb = im * bw[e];
    const float wsp = im * sw[e];
    const float* c = cp + (size_t)e * 5;
    const float c0 = c[0], c1 = c[1], c2 = c[2], c3 = c[3], c4 = c[4];
    const float q0 = (0.54336160f * c0 + 0.31713055f * c1 + 0.11226386f * c2 +
                      0.02410431f * c3 + 0.00313908f * c4) * wsp;
    const float q1 = (0.06493530f * c0 + 0.17651242f * c1 + 0.29101978f * c2 +
                      0.29101978f * c3 + 0.17651242f * c4) * wsp;
    const float q2 = (0.00313908f * c0 + 0.02410431f * c1 + 0.11226386f * c2 +
                      0.31713055f * c3 + 0.54336160f * c4) * wsp;
    ushort4 v;
    v.x = f2bf(wb); v.y = f2bf(q0); v.z = f2bf(q1); v.w = f2bf(q2);
    *reinterpret_cast<ushort4*>(Wt + (size_t)o * KDIM + i * 4) = v;
  }
}

// ---------------------------------------------------------------------------
// GEMM: C = A[M,K] * Wt[N,K]^T, bf16 MFMA, BK=64, 4 waves (2x2), T1 swizzle.
// Sync (T3/T4, R5-verified): 2-tile prefetch, counted s_waitcnt vmcnt(6),
// raw s_barrier; never drains vmcnt to 0 in the main loop.
// NEW (T2-analog via m173): chunk-column XOR swizzle to kill the ~4-way
// ds_read_b128 bank conflicts (3.1M cyc measured R2/R7). Chunk c of row r is
// staged from global column (c ^ (r&3)) — LDS dest stays LINEAR (gload_lds
// rule #21) — and read back at kg = ((l>>4) ^ (l&3))*8. XORs cancel: lane l
// still receives k-group l>>4, so MFMA operands are bit-identical.
// Bank math: 8-lane read groups now span 4 disjoint bank-quads (2-way, free
// per m136) instead of 2 quads (4-way).
// ---------------------------------------------------------------------------
__device__ __forceinline__ void gload16(const void* g, void* lds) {
  __builtin_amdgcn_global_load_lds(
      (const __attribute__((address_space(1))) unsigned int*)g,
      (__attribute__((address_space(3))) unsigned int*)lds,
      16, 0, 0);
}

#define WAITV(n) asm volatile("s_waitcnt vmcnt(" #n ")" ::: "memory")

__global__ __launch_bounds__(256, 3) void gemm(const unsigned short* __restrict__ A,
                                               const unsigned short* __restrict__ Wt,
                                               float* __restrict__ C) {
  // [buf][kh][rows][32] elems: A 2*2*128*32, B 2*2*64*32  -> 48 KB total
  __shared__ __align__(16) unsigned short As[2 * 8192];
  __shared__ __align__(16) unsigned short Bs[2 * 4096];

  // T1: XCD-aware swizzle (8 XCDs, 512 blocks, bijective since 512%8==0).
  const int bid = blockIdx.x;
  const int nb = (bid & 7) * 64 + (bid >> 3);
  const int mt = nb >> 3;
  const int nt = nb & 7;
  const int m0 = mt * BM;
  const int n0 = nt * BN;

  const int t = threadIdx.x;
  const int l = t & 63;
  const int w = t >> 6;
  const int wm = w >> 1;     // 2 m-halves of 64 rows
  const int wn = w & 1;      // 2 n-halves of 32 cols
  const int lr = l & 15;
  // Swizzled k-group: LDS chunk (l>>4)^(l&3) of row lr holds global k-group
  // l>>4 (row&3 == l&3 for all fragment rows: wm*64, m*16, n*16 are mult of 4).
  const int kg = ((l >> 4) ^ (l & 3)) * 8;

  f32x4 acc[4][2] = {};

  // Staging slot maps. LDS written linearly in slot order (HW rule); the
  // global source column is pre-swizzled: chunk col c_g = c ^ (row&3).
  const unsigned short* gA[4];
  unsigned short* lA[2][4];
  const unsigned short* gB[2];
  unsigned short* lB[2][2];
#pragma unroll
  for (int i = 0; i < 4; ++i) {
    const int s = t + 256 * i;
    const int kh = s >> 9, row = (s >> 2) & 127, c = s & 3;
    gA[i] = A + (size_t)(m0 + row) * KDIM + kh * 32 + ((c ^ (row & 3)) * 8);
    lA[0][i] = As + s * 8;
    lA[1][i] = As + 8192 + s * 8;
  }
#pragma unroll
  for (int i = 0; i < 2; ++i) {
    const int s = t + 256 * i;
    const int kh = s >> 8, row = (s >> 2) & 63, c = s & 3;
    gB[i] = Wt + (size_t)(n0 + row) * KDIM + kh * 32 + ((c ^ (row & 3)) * 8);
    lB[0][i] = Bs + s * 8;
    lB[1][i] = Bs + 4096 + s * 8;
  }

  const int aoff = (wm * 64 + lr) * 32 + kg;   // + m*512 + kh*4096
  const int boff = (wn * 32 + lr) * 32 + kg;   // + n*512 + kh*2048

#define STAGE(buf, tile) do {                                                  \
    const int ko = (tile) * BK;                                                \
    _Pragma("unroll") for (int i = 0; i < 4; ++i) gload16(gA[i] + ko, lA[buf][i]); \
    _Pragma("unroll") for (int i = 0; i < 2; ++i) gload16(gB[i] + ko, lB[buf][i]); \
  } while (0)

#define COMPUTE(buf) do {                                                      \
    const unsigned short* Ab = As + (buf) * 8192;                              \
    const unsigned short* Bb = Bs + (buf) * 4096;                              \
    bf16x8 af[2][4], bfr[2][2];                                                \
    _Pragma("unroll") for (int h = 0; h < 2; ++h)                              \
      _Pragma("unroll") for (int m = 0; m < 4; ++m)                            \
        af[h][m] = *reinterpret_cast<const bf16x8*>(Ab + h * 4096 + aoff + m * 512); \
    _Pragma("unroll") for (int h = 0; h < 2; ++h)                              \
      _Pragma("unroll") for (int n = 0; n < 2; ++n)                            \
        bfr[h][n] = *reinterpret_cast<const bf16x8*>(Bb + h * 2048 + boff + n * 512); \
    _Pragma("unroll") for (int h = 0; h < 2; ++h)                              \
      _Pragma("unroll") for (int m = 0; m < 4; ++m)                            \
        _Pragma("unroll") for (int n = 0; n < 2; ++n)                          \
          acc[m][n] = __builtin_amdgcn_mfma_f32_16x16x32_bf16(af[h][m], bfr[h][n], acc[m][n], 0, 0, 0); \
  } while (0)

  // 32 K-tiles, 2 tiles in flight. Static buf indices everywhere (rule #20).
  STAGE(0, 0);
  STAGE(1, 1);
#pragma unroll 1
  for (int tl = 0; tl < 28; tl += 2) {
    WAITV(6); __builtin_amdgcn_s_barrier();
    COMPUTE(0);
    __builtin_amdgcn_s_barrier();
    STAGE(0, tl + 2);
    WAITV(6); __builtin_amdgcn_s_barrier();
    COMPUTE(1);
    __builtin_amdgcn_s_barrier();
    STAGE(1, tl + 3);
  }
  // tiles 28..31 (stages 30,31 issued here; never vmcnt(0) until the end)
  WAITV(6); __builtin_amdgcn_s_barrier();
  COMPUTE(0);
  __builtin_amdgcn_s_barrier();
  STAGE(0, 30);
  WAITV(6); __builtin_amdgcn_s_barrier();
  COMPUTE(1);
  __builtin_amdgcn_s_barrier();
  STAGE(1, 31);
  WAITV(6); __builtin_amdgcn_s_barrier();
  COMPUTE(0);
  WAITV(0); __builtin_amdgcn_s_barrier();
  COMPUTE(1);

#undef STAGE
#undef COMPUTE

  // Epilogue: C/D layout col = lane&15, row = (lane>>4)*4 + reg [m89]
#pragma unroll
  for (int m = 0; m < 4; ++m) {
#pragma unroll
    for (int n = 0; n < 2; ++n) {
      const int col = n0 + wn * 32 + n * 16 + lr;
      const int rbase = m0 + wm * 64 + m * 16 + (l >> 4) * 4;
#pragma unroll
      for (int r = 0; r < 4; ++r)
        C[(size_t)(rbase + r) * O_DIM + col] = acc[m][n][r];
    }
  }
}

// ---------------------------------------------------------------------------
extern "C" void kernel_launch(void* const* d_in, const int* in_sizes, int n_in,
                              void* d_out, int out_size, void* d_ws, size_t ws_size,
                              hipStream_t stream) {
  const float* x   = (const float*)d_in[0];
  const float* cp  = (const float*)d_in[1];
  const float* bw  = (const float*)d_in[2];
  const float* sw  = (const float*)d_in[3];
  const float* imp = (const float*)d_in[4];
  float* out = (float*)d_out;

  unsigned short* Abuf = (unsigned short*)d_ws;                  // 32 MB bf16
  unsigned short* Wbuf = Abuf + (size_t)B_DIM * KDIM;            //  2 MB bf16

  build_aw<<<4096 + 1024, 256, 0, stream>>>(x, cp, bw, sw, imp, Abuf, Wbuf);
  gemm<<<(B_DIM / BM) * (O_DIM / BN), 256, 0, stream>>>(Abuf, Wbuf, out);
}

// Round 9
// 109.200 us; speedup vs baseline: 1.2708x; 1.0045x over previous
//
#include <hip/hip_runtime.h>
#include <stdint.h>

// Problem dims
#define B_DIM 8192
#define I_DIM 512
#define O_DIM 512
#define KDIM  2048   // I_DIM * 4 features: {silu, u0, u1, u2}

// GEMM tile
#define BM 128
#define BN 64
#define BK 64        // two 32-wide halves; LDS layout [kh][rows][32]

using bf16x8 = __attribute__((ext_vector_type(8))) short;
using f32x4  = __attribute__((ext_vector_type(4))) float;

__device__ __forceinline__ unsigned short f2bf(float f) {
  union { float f; unsigned int u; } c; c.f = f;
  unsigned int x = c.u;
  unsigned int r = (x + 0x7fffu + ((x >> 16) & 1u)) >> 16;  // RNE
  return (unsigned short)r;
}

// ---------------------------------------------------------------------------
// Fused prologue. Blocks [0, 4096): A[b][i*4+{0..3}] = {silu(x), u0, u1, u2}.
// Blocks [4096, 5120): Wt[o][i*4+0]=imp*bw ; Wt[o][i*4+1+g]=(BASIS[g]·cp)*imp*sw
// ---------------------------------------------------------------------------
__global__ __launch_bounds__(256) void build_aw(const float* __restrict__ x,
                                                const float* __restrict__ cp,
                                                const float* __restrict__ bw,
                                                const float* __restrict__ sw,
                                                const float* __restrict__ imp,
                                                unsigned short* __restrict__ A,
                                                unsigned short* __restrict__ Wt) {
  if (blockIdx.x < 4096) {
    const int idx = blockIdx.x * 256 + threadIdx.x;
    const int b = idx >> 7;
    const int q = idx & 127;
    const float4 xv = *reinterpret_cast<const float4*>(x + (size_t)b * I_DIM + q * 4);
    union { unsigned short us[16]; uint4 v[2]; } out;
    const float xs[4] = {xv.x, xv.y, xv.z, xv.w};
#pragma unroll
    for (int j = 0; j < 4; ++j) {
      const float xf = xs[j];
      const float s = xf / (1.0f + __expf(-xf));          // silu, f32
      const float xc = fminf(fmaxf(xf, -1.0f), 1.0f);
      const float g = xc + 1.0f;                          // grid_idx in [0,2]
      int il = (int)floorf(g);
      if (il > 2) il = 2;
      const float fr = g - (float)il;
      int ih = il + (fr > 0.0f ? 1 : 0);
      if (ih > 2) ih = 2;
      const float u0 = (il == 0 ? 1.0f - fr : 0.0f) + (ih == 0 ? fr : 0.0f);
      const float u1 = (il == 1 ? 1.0f - fr : 0.0f) + (ih == 1 ? fr : 0.0f);
      const float u2 = (il == 2 ? 1.0f - fr : 0.0f) + (ih == 2 ? fr : 0.0f);
      out.us[j * 4 + 0] = f2bf(s);
      out.us[j * 4 + 1] = f2bf(u0);
      out.us[j * 4 + 2] = f2bf(u1);
      out.us[j * 4 + 3] = f2bf(u2);
    }
    uint4* dst = reinterpret_cast<uint4*>(A + (size_t)b * KDIM + q * 16);
    dst[0] = out.v[0];
    dst[1] = out.v[1];
  } else {
    const int idx = (blockIdx.x - 4096) * 256 + threadIdx.x;
    const int i = idx >> 9;
    const int o = idx & 511;
    const int e = i * O_DIM + o;
    const float im = imp[e];
    const float wb = im * bw[e];
    const float wsp = im * sw[e];
    const float* c = cp + (size_t)e * 5;
    const float c0 = c[0], c1 = c[1], c2 = c[2], c3 = c[3], c4 = c[4];
    const float q0 = (0.54336160f * c0 + 0.31713055f * c1 + 0.11226386f * c2 +
                      0.02410431f * c3 + 0.00313908f * c4) * wsp;
    const float q1 = (0.06493530f * c0 + 0.17651242f * c1 + 0.29101978f * c2 +
                      0.29101978f * c3 + 0.17651242f * c4) * wsp;
    const float q2 = (0.00313908f * c0 + 0.02410431f * c1 + 0.11226386f * c2 +
                      0.31713055f * c3 + 0.54336160f * c4) * wsp;
    ushort4 v;
    v.x = f2bf(wb); v.y = f2bf(q0); v.z = f2bf(q1); v.w = f2bf(q2);
    *reinterpret_cast<ushort4*>(Wt + (size_t)o * KDIM + i * 4) = v;
  }
}

// ---------------------------------------------------------------------------
// GEMM: C = A[M,K] * Wt[N,K]^T, bf16 MFMA, BK=64, 4 waves (2x2), T1 swizzle.
// Sync (T3/T4, R5-verified best): 2-tile prefetch, counted s_waitcnt vmcnt(6),
// raw s_barrier; never drains vmcnt to 0 in the main loop.
// CORRECTED T2 swizzle (R8's was a no-op — it XORed with l&3, constant within
// the true conflict group {l,l+4,l+8,l+12}): rows are 64 B so the bank map
// repeats every 2 ROWS; the spreading key is the row-PAIR index (row>>1)&3.
// Stage chunk c from global chunk c^((row>>1)&3) (LDS dest linear, rule #21);
// read back kg = ((l>>4) ^ ((l>>1)&3))*8  ((l>>1)&3 == (lr>>1)&3 since bit4
// of l does not enter bits 1-2).  Involution cancels -> operands identical.
// Bank check: any 16 consecutive lanes hit 8 distinct bank-quads x 2 lanes
// (2-way = free, m136) instead of 4-way on quads {c*4}.
// ---------------------------------------------------------------------------
__device__ __forceinline__ void gload16(const void* g, void* lds) {
  __builtin_amdgcn_global_load_lds(
      (const __attribute__((address_space(1))) unsigned int*)g,
      (__attribute__((address_space(3))) unsigned int*)lds,
      16, 0, 0);
}

#define WAITV(n) asm volatile("s_waitcnt vmcnt(" #n ")" ::: "memory")

__global__ __launch_bounds__(256, 3) void gemm(const unsigned short* __restrict__ A,
                                               const unsigned short* __restrict__ Wt,
                                               float* __restrict__ C) {
  // [buf][kh][rows][32] elems: A 2*2*128*32, B 2*2*64*32  -> 48 KB total
  __shared__ __align__(16) unsigned short As[2 * 8192];
  __shared__ __align__(16) unsigned short Bs[2 * 4096];

  // T1: XCD-aware swizzle (8 XCDs, 512 blocks, bijective since 512%8==0).
  const int bid = blockIdx.x;
  const int nb = (bid & 7) * 64 + (bid >> 3);
  const int mt = nb >> 3;
  const int nt = nb & 7;
  const int m0 = mt * BM;
  const int n0 = nt * BN;

  const int t = threadIdx.x;
  const int l = t & 63;
  const int w = t >> 6;
  const int wm = w >> 1;     // 2 m-halves of 64 rows
  const int wn = w & 1;      // 2 n-halves of 32 cols
  const int lr = l & 15;
  // Corrected swizzled k-group: chunk (l>>4)^((l>>1)&3) of row lr holds
  // global k-group l>>4.  Fragment rows wm*64+m*16+lr keep (row>>1)&3 ==
  // (lr>>1)&3 (offsets are multiples of 16).
  const int kg = ((l >> 4) ^ ((l >> 1) & 3)) * 8;

  f32x4 acc[4][2] = {};

  // Staging slot maps. LDS written linearly in slot order (HW rule); the
  // global source chunk is pre-swizzled: c_g = c ^ ((row>>1)&3).
  const unsigned short* gA[4];
  unsigned short* lA[2][4];
  const unsigned short* gB[2];
  unsigned short* lB[2][2];
#pragma unroll
  for (int i = 0; i < 4; ++i) {
    const int s = t + 256 * i;
    const int kh = s >> 9, row = (s >> 2) & 127, c = s & 3;
    gA[i] = A + (size_t)(m0 + row) * KDIM + kh * 32 + ((c ^ ((row >> 1) & 3)) * 8);
    lA[0][i] = As + s * 8;
    lA[1][i] = As + 8192 + s * 8;
  }
#pragma unroll
  for (int i = 0; i < 2; ++i) {
    const int s = t + 256 * i;
    const int kh = s >> 8, row = (s >> 2) & 63, c = s & 3;
    gB[i] = Wt + (size_t)(n0 + row) * KDIM + kh * 32 + ((c ^ ((row >> 1) & 3)) * 8);
    lB[0][i] = Bs + s * 8;
    lB[1][i] = Bs + 4096 + s * 8;
  }

  const int aoff = (wm * 64 + lr) * 32 + kg;   // + m*512 + kh*4096
  const int boff = (wn * 32 + lr) * 32 + kg;   // + n*512 + kh*2048

#define STAGE(buf, tile) do {                                                  \
    const int ko = (tile) * BK;                                                \
    _Pragma("unroll") for (int i = 0; i < 4; ++i) gload16(gA[i] + ko, lA[buf][i]); \
    _Pragma("unroll") for (int i = 0; i < 2; ++i) gload16(gB[i] + ko, lB[buf][i]); \
  } while (0)

#define COMPUTE(buf) do {                                                      \
    const unsigned short* Ab = As + (buf) * 8192;                              \
    const unsigned short* Bb = Bs + (buf) * 4096;                              \
    bf16x8 af[2][4], bfr[2][2];                                                \
    _Pragma("unroll") for (int h = 0; h < 2; ++h)                              \
      _Pragma("unroll") for (int m = 0; m < 4; ++m)                            \
        af[h][m] = *reinterpret_cast<const bf16x8*>(Ab + h * 4096 + aoff + m * 512); \
    _Pragma("unroll") for (int h = 0; h < 2; ++h)                              \
      _Pragma("unroll") for (int n = 0; n < 2; ++n)                            \
        bfr[h][n] = *reinterpret_cast<const bf16x8*>(Bb + h * 2048 + boff + n * 512); \
    _Pragma("unroll") for (int h = 0; h < 2; ++h)                              \
      _Pragma("unroll") for (int m = 0; m < 4; ++m)                            \
        _Pragma("unroll") for (int n = 0; n < 2; ++n)                          \
          acc[m][n] = __builtin_amdgcn_mfma_f32_16x16x32_bf16(af[h][m], bfr[h][n], acc[m][n], 0, 0, 0); \
  } while (0)

  // 32 K-tiles, 2 tiles in flight. Static buf indices everywhere (rule #20).
  STAGE(0, 0);
  STAGE(1, 1);
#pragma unroll 1
  for (int tl = 0; tl < 28; tl += 2) {
    WAITV(6); __builtin_amdgcn_s_barrier();
    COMPUTE(0);
    __builtin_amdgcn_s_barrier();
    STAGE(0, tl + 2);
    WAITV(6); __builtin_amdgcn_s_barrier();
    COMPUTE(1);
    __builtin_amdgcn_s_barrier();
    STAGE(1, tl + 3);
  }
  // tiles 28..31 (stages 30,31 issued here; never vmcnt(0) until the end)
  WAITV(6); __builtin_amdgcn_s_barrier();
  COMPUTE(0);
  __builtin_amdgcn_s_barrier();
  STAGE(0, 30);
  WAITV(6); __builtin_amdgcn_s_barrier();
  COMPUTE(1);
  __builtin_amdgcn_s_barrier();
  STAGE(1, 31);
  WAITV(6); __builtin_amdgcn_s_barrier();
  COMPUTE(0);
  WAITV(0); __builtin_amdgcn_s_barrier();
  COMPUTE(1);

#undef STAGE
#undef COMPUTE

  // Epilogue: C/D layout col = lane&15, row = (lane>>4)*4 + reg [m89]
#pragma unroll
  for (int m = 0; m < 4; ++m) {
#pragma unroll
    for (int n = 0; n < 2; ++n) {
      const int col = n0 + wn * 32 + n * 16 + lr;
      const int rbase = m0 + wm * 64 + m * 16 + (l >> 4) * 4;
#pragma unroll
      for (int r = 0; r < 4; ++r)
        C[(size_t)(rbase + r) * O_DIM + col] = acc[m][n][r];
    }
  }
}

// ---------------------------------------------------------------------------
extern "C" void kernel_launch(void* const* d_in, const int* in_sizes, int n_in,
                              void* d_out, int out_size, void* d_ws, size_t ws_size,
                              hipStream_t stream) {
  const float* x   = (const float*)d_in[0];
  const float* cp  = (const float*)d_in[1];
  const float* bw  = (const float*)d_in[2];
  const float* sw  = (const float*)d_in[3];
  const float* imp = (const float*)d_in[4];
  float* out = (float*)d_out;

  unsigned short* Abuf = (unsigned short*)d_ws;                  // 32 MB bf16
  unsigned short* Wbuf = Abuf + (size_t)B_DIM * KDIM;            //  2 MB bf16

  build_aw<<<4096 + 1024, 256, 0, stream>>>(x, cp, bw, sw, imp, Abuf, Wbuf);
  gemm<<<(B_DIM / BM) * (O_DIM / BN), 256, 0, stream>>>(Abuf, Wbuf, out);
}